// Round 15
// baseline (693.480 us; speedup 1.0000x reference)
//
#include <hip/hip_runtime.h>
#include <math.h>

#define SD 7
#define HID 64
#define NITER 10

typedef float f16s __attribute__((ext_vector_type(16)));
typedef float f8s  __attribute__((ext_vector_type(8)));
typedef float f4   __attribute__((ext_vector_type(4)));
typedef float f2   __attribute__((ext_vector_type(2)));

#define REP7(M)  M(0) M(1) M(2) M(3) M(4) M(5) M(6)
#define REP8(M)  M(0) M(1) M(2) M(3) M(4) M(5) M(6) M(7)
#define REP15(M) M(1) M(2) M(3) M(4) M(5) M(6) M(7) M(8) M(9) M(10) M(11) M(12) M(13) M(14) M(15)
#define REP16(M) M(0) M(1) M(2) M(3) M(4) M(5) M(6) M(7) M(8) M(9) M(10) M(11) M(12) M(13) M(14) M(15)
#define AP8(M, ...) M(0, __VA_ARGS__) M(1, __VA_ARGS__) M(2, __VA_ARGS__) M(3, __VA_ARGS__) \
    M(4, __VA_ARGS__) M(5, __VA_ARGS__) M(6, __VA_ARGS__) M(7, __VA_ARGS__)

// ---- SMEM loads: used ONCE (Be2 precompute + ob), outside the hot loop ----
#define SLOAD4(d0, d1, d2, d3, p, o0, o1, o2, o3) \
    asm volatile("s_load_dwordx16 %0, %4, %5\n\t" \
                 "s_load_dwordx16 %1, %4, %6\n\t" \
                 "s_load_dwordx16 %2, %4, %7\n\t" \
                 "s_load_dwordx16 %3, %4, %8\n\t" \
                 "s_waitcnt lgkmcnt(0)" \
                 : "=&s"(d0), "=&s"(d1), "=&s"(d2), "=&s"(d3) \
                 : "s"(p), "i"(o0), "i"(o1), "i"(o2), "i"(o3));

#define SLOADX8(d0, p) \
    asm volatile("s_load_dwordx8 %0, %1, 0\n\t" \
                 "s_waitcnt lgkmcnt(0)" \
                 : "=&s"(d0) : "s"(p));

// ---- LDS uniform 64B read: 4 x b128 contiguous, wait inside (r10/r11-proven) ----
#define LDS4U(A, B, C, D, ADDR) \
    asm volatile("ds_read_b128 %0, %4 offset:0\n\t" \
                 "ds_read_b128 %1, %4 offset:16\n\t" \
                 "ds_read_b128 %2, %4 offset:32\n\t" \
                 "ds_read_b128 %3, %4 offset:48\n\t" \
                 "s_waitcnt lgkmcnt(0)" \
                 : "=&v"(A), "=&v"(B), "=&v"(C), "=&v"(D) : "v"(ADDR));

// ---- pk helpers ----
#define PKW(W, e)   __builtin_shufflevector((W), (W), 2*(e), 2*(e)+1)   // f16s -> f2
#define SHF2(V, h_) __builtin_shufflevector((V), (V), 2*(h_), 2*(h_)+1) // f4  -> f2

// SGPR-pair weight (init path only)
#define PKFMA_ACC(acc, ws, mv) \
    asm("v_pk_fma_f32 %0, %1, %2, %0" : "+v"(acc) : "s"(ws), "v"(mv));
// all-VGPR forms (hot loop)
#define PKFMA_ACCV(acc, wv, mv) \
    asm("v_pk_fma_f32 %0, %1, %2, %0" : "+v"(acc) : "v"(wv), "v"(mv));
#define PKFMA_NEWV(dst, wv, mv, cv) \
    asm("v_pk_fma_f32 %0, %1, %2, %3" : "=v"(dst) : "v"(wv), "v"(mv), "v"(cv));
#define PKFMA_GLV(g, tv, lsv, lbv) \
    asm("v_pk_fma_f32 %0, %1, %2, %3" : "=v"(g) : "v"(tv), "v"(lsv), "v"(lbv));

#define PKROW_E(e, arr, base, m2v, W) PKFMA_ACC((arr)[(base)+(e)], PKW(W, e), m2v)
#define PKROW(arr, m2v, wa, wb, wc, wd) \
    AP8(PKROW_E, arr, 0,  m2v, wa) AP8(PKROW_E, arr, 8,  m2v, wb) \
    AP8(PKROW_E, arr, 16, m2v, wc) AP8(PKROW_E, arr, 24, m2v, wd)

__global__ void transpose_ow_kernel(const float* __restrict__ ow,
                                    float* __restrict__ owt) {
    int t = threadIdx.x;
    if (t < HID * SD) owt[(t % SD) * HID + (t / SD)] = ow[t];   // owT[i][j]
}

__global__ __launch_bounds__(256) __attribute__((amdgpu_waves_per_eu(2)))
void strange_loop_kernel(const float* __restrict__ s7,
                         const float* __restrict__ w0,
                         const float* __restrict__ b0,
                         const float* __restrict__ lns,
                         const float* __restrict__ lnb,
                         const float* __restrict__ owt,
                         const float* __restrict__ ob,
                         float* __restrict__ out_mu,
                         float* __restrict__ out_cv,
                         int Bn)
{
    __shared__ __align__(16) float w0s[SD * HID];  // mu-rows k=0..6     1792 B
    __shared__ __align__(16) float owI[SD * HID];  // owT[7][64]         1792 B
    __shared__ __align__(16) float lnI[2 * HID];   // interleaved ls/lb   512 B

    const int tid = threadIdx.x;
    {
        int t2 = tid + 256;
        if (tid < SD * HID) { w0s[tid] = w0[tid]; owI[tid] = owt[tid]; }
        if (t2  < SD * HID) { w0s[t2]  = w0[t2];  owI[t2]  = owt[t2]; }
        if (tid < 2 * HID) {
            int p = tid >> 2, r = tid & 3;   // lnI[4p..4p+3] = ls[2p],ls[2p+1],lb[2p],lb[2p+1]
            lnI[tid] = (r < 2) ? lns[2 * p + r] : lnb[2 * p + (r - 2)];
        }
    }
    __syncthreads();

    const unsigned aw0 = (unsigned)(size_t)(&w0s[0]);
    const unsigned aow = (unsigned)(size_t)(&owI[0]);
    const unsigned aln = (unsigned)(size_t)(&lnI[0]);

    int row = blockIdx.x * blockDim.x + tid;
    if (row >= Bn) row = Bn - 1;   // clamp: uniform control flow, dup write benign

    float s[SD];
#define LD_S(k) s[k] = s7[(size_t)row * SD + (k)];
    REP7(LD_S)

    // ---- iteration-invariant: Be2 = b0 + sum_k s[k]*W0[7+k][.] (once; SGPR path) ----
    f2 Be2[32];
    {
        f16s ba, bb, bc, bd;
        SLOAD4(ba, bb, bc, bd, b0, 0, 64, 128, 192)
#define B0P(e, W, base) Be2[(base)+(e)] = PKW(W, e);
        AP8(B0P, ba, 0) AP8(B0P, bb, 8) AP8(B0P, bc, 16) AP8(B0P, bd, 24)
    }
#define BIK(k) { f16s wa, wb, wc, wd; \
    SLOAD4(wa, wb, wc, wd, w0, (7+(k))*256, (7+(k))*256+64, (7+(k))*256+128, (7+(k))*256+192) \
    f2 m2 = {s[k], s[k]}; \
    PKROW(Be2, m2, wa, wb, wc, wd) }
    REP7(BIK)

    f8s obv;
    SLOADX8(obv, ob)

    float mu[SD];
#define INITMU(i) mu[i] = 0.37796447300922720f;   // 1/sqrt(7)
    REP7(INITMU)
    float conv = 0.0f;

#pragma unroll 1
    for (int it = 0; it < NITER; ++it) {
        // ---- fc0 packed, weights from LDS (VGPR pairs): xe2 = Be2 + sum_k mu[k]*W0[k] ----
        f2 xe2[32];
#define FCB0(bb) { f4 A, B, C, D; LDS4U(A, B, C, D, aw0 + (bb)*64) \
        PKFMA_NEWV(xe2[(bb)*8+0], SHF2(A,0), m2, Be2[(bb)*8+0]) \
        PKFMA_NEWV(xe2[(bb)*8+1], SHF2(A,1), m2, Be2[(bb)*8+1]) \
        PKFMA_NEWV(xe2[(bb)*8+2], SHF2(B,0), m2, Be2[(bb)*8+2]) \
        PKFMA_NEWV(xe2[(bb)*8+3], SHF2(B,1), m2, Be2[(bb)*8+3]) \
        PKFMA_NEWV(xe2[(bb)*8+4], SHF2(C,0), m2, Be2[(bb)*8+4]) \
        PKFMA_NEWV(xe2[(bb)*8+5], SHF2(C,1), m2, Be2[(bb)*8+5]) \
        PKFMA_NEWV(xe2[(bb)*8+6], SHF2(D,0), m2, Be2[(bb)*8+6]) \
        PKFMA_NEWV(xe2[(bb)*8+7], SHF2(D,1), m2, Be2[(bb)*8+7]) }
        { f2 m2 = {mu[0], mu[0]}; FCB0(0) FCB0(1) FCB0(2) FCB0(3) }
#define FCBK(kk, bb) { f4 A, B, C, D; LDS4U(A, B, C, D, aw0 + (kk)*256 + (bb)*64) \
        PKFMA_ACCV(xe2[(bb)*8+0], SHF2(A,0), m2) \
        PKFMA_ACCV(xe2[(bb)*8+1], SHF2(A,1), m2) \
        PKFMA_ACCV(xe2[(bb)*8+2], SHF2(B,0), m2) \
        PKFMA_ACCV(xe2[(bb)*8+3], SHF2(B,1), m2) \
        PKFMA_ACCV(xe2[(bb)*8+4], SHF2(C,0), m2) \
        PKFMA_ACCV(xe2[(bb)*8+5], SHF2(C,1), m2) \
        PKFMA_ACCV(xe2[(bb)*8+6], SHF2(D,0), m2) \
        PKFMA_ACCV(xe2[(bb)*8+7], SHF2(D,1), m2) }
#define FCROWK(kk) { f2 m2 = {mu[kk], mu[kk]}; FCBK(kk,0) FCBK(kk,1) FCBK(kk,2) FCBK(kk,3) }
        FCROWK(1) FCROWK(2) FCROWK(3) FCROWK(4) FCROWK(5) FCROWK(6)

        // ---- LayerNorm (r12-verbatim packed two-pass) ----
        f2 P01 = xe2[0], P23 = xe2[1];
#define SACE(q) P01 += xe2[2*(q)]; P23 += xe2[2*(q)+1];
        REP15(SACE)
        float mean = ((P01.x + P01.y) + (P23.x + P23.y)) * (1.0f / HID);

        f2 V01 = {0.f, 0.f}, V23 = {0.f, 0.f};
        {
            f2 mn2 = {mean, mean};
#define VACE(q) { f2 a0 = xe2[2*(q)] - mn2; f2 a1 = xe2[2*(q)+1] - mn2; \
            V01 = __builtin_elementwise_fma(a0, a0, V01); \
            V23 = __builtin_elementwise_fma(a1, a1, V23); \
            xe2[2*(q)] = a0; xe2[2*(q)+1] = a1; }
            REP16(VACE)
        }
        float var  = ((V01.x + V01.y) + (V23.x + V23.y)) * (1.0f / HID);
        float rstd = 1.0f / sqrtf(var + 1e-6f);

        // ---- scale/shift + GELU (r12 arithmetic; params from LDS as VGPR pairs) ----
        {
            const f2 rs2 = {rstd, rstd};
            const f2 kB2 = {0.044715f, 0.044715f};
            const f2 kC2 = {-1.5957691216057308f, -1.5957691216057308f};
#define GEL1V(p, lsv, lbv) { \
            f2 t = xe2[p] * rs2; \
            f2 g; PKFMA_GLV(g, t, lsv, lbv) \
            f2 g2 = g * g; f2 g3 = g2 * g; \
            f2 z = __builtin_elementwise_fma(kB2, g3, g) * kC2; \
            float e0 = __expf(z.x), e1 = __expf(z.y); \
            xe2[p].x = __fdividef(g.x, 1.0f + e0); \
            xe2[p].y = __fdividef(g.y, 1.0f + e1); }
#define GELQ(q) { f4 L0, L1, L2, L3; LDS4U(L0, L1, L2, L3, aln + (q)*64) \
            GEL1V(4*(q)+0, SHF2(L0,0), SHF2(L0,1)) \
            GEL1V(4*(q)+1, SHF2(L1,0), SHF2(L1,1)) \
            GEL1V(4*(q)+2, SHF2(L2,0), SHF2(L2,1)) \
            GEL1V(4*(q)+3, SHF2(L3,0), SHF2(L3,1)) }
            REP8(GELQ)
        }

        // ---- out matmul packed, owT rows from LDS: u[i] = sum_p xe2[p]*owT[i].p ----
        float u[SD];
#define OUTB(bb) { f4 A, B, C, D; LDS4U(A, B, C, D, aow + I_*256 + (bb)*64) \
        PKFMA_ACCV(acc, SHF2(A,0), xe2[(bb)*8+0]) \
        PKFMA_ACCV(acc, SHF2(A,1), xe2[(bb)*8+1]) \
        PKFMA_ACCV(acc, SHF2(B,0), xe2[(bb)*8+2]) \
        PKFMA_ACCV(acc, SHF2(B,1), xe2[(bb)*8+3]) \
        PKFMA_ACCV(acc, SHF2(C,0), xe2[(bb)*8+4]) \
        PKFMA_ACCV(acc, SHF2(C,1), xe2[(bb)*8+5]) \
        PKFMA_ACCV(acc, SHF2(D,0), xe2[(bb)*8+6]) \
        PKFMA_ACCV(acc, SHF2(D,1), xe2[(bb)*8+7]) }
#define OUTI(i) { const int I_ = (i); f2 acc = {0.f, 0.f}; \
        OUTB(0) OUTB(1) OUTB(2) OUTB(3) \
        u[i] = (acc.x + acc.y) + obv[i]; }
        REP7(OUTI)

        // ---- L2 normalize (identical) ----
        float ss = 0.f;
#define SSQ(i) ss = fmaf(u[i], u[i], ss);
        REP7(SSQ)
        float inv = __fdividef(1.0f, sqrtf(ss) + 1e-8f);

        // ---- damped update + convergence (identical) ----
        float dd = 0.f;
#define UPD(i) { float un = u[i] * inv; float mn = 0.5f * mu[i] + 0.5f * un; \
        float d = mn - mu[i]; dd = fmaf(d, d, dd); mu[i] = mn; }
        REP7(UPD)
        if (sqrtf(dd) < 1e-4f) conv = 1.0f;
    }

#define ST(i) out_mu[(size_t)row * SD + (i)] = mu[i];
    REP7(ST)
    out_cv[row] = conv;
}

extern "C" void kernel_launch(void* const* d_in, const int* in_sizes, int n_in,
                              void* d_out, int out_size, void* d_ws, size_t ws_size,
                              hipStream_t stream) {
    const float* s7  = (const float*)d_in[0];
    const float* w0  = (const float*)d_in[1];
    const float* b0  = (const float*)d_in[2];
    const float* lns = (const float*)d_in[3];
    const float* lnb = (const float*)d_in[4];
    const float* ow  = (const float*)d_in[5];
    const float* ob  = (const float*)d_in[6];
    const int Bn = in_sizes[0] / SD;

    float* out_mu = (float*)d_out;
    float* out_cv = out_mu + (size_t)Bn * SD;
    float* owt    = (float*)d_ws;            // 448 floats = 1792 B scratch

    hipLaunchKernelGGL(transpose_ow_kernel, dim3(1), dim3(512), 0, stream, ow, owt);

    const int block = 256;
    const int grid  = (Bn + block - 1) / block;
    hipLaunchKernelGGL(strange_loop_kernel, dim3(grid), dim3(block), 0, stream,
                       s7, w0, b0, lns, lnb, owt, ob, out_mu, out_cv, Bn);
}

// Round 16
// 588.629 us; speedup vs baseline: 1.1781x; 1.1781x over previous
//
#include <hip/hip_runtime.h>
#include <math.h>

#define SD 7
#define HID 64
#define NITER 10

typedef float f16s __attribute__((ext_vector_type(16)));
typedef float f8s  __attribute__((ext_vector_type(8)));
typedef float f4   __attribute__((ext_vector_type(4)));
typedef float f2   __attribute__((ext_vector_type(2)));

#define REP7(M)  M(0) M(1) M(2) M(3) M(4) M(5) M(6)
#define REP15(M) M(1) M(2) M(3) M(4) M(5) M(6) M(7) M(8) M(9) M(10) M(11) M(12) M(13) M(14) M(15)
#define REP16(M) M(0) M(1) M(2) M(3) M(4) M(5) M(6) M(7) M(8) M(9) M(10) M(11) M(12) M(13) M(14) M(15)
#define AP8(M, ...) M(0, __VA_ARGS__) M(1, __VA_ARGS__) M(2, __VA_ARGS__) M(3, __VA_ARGS__) \
    M(4, __VA_ARGS__) M(5, __VA_ARGS__) M(6, __VA_ARGS__) M(7, __VA_ARGS__)

// ---- SMEM loads (volatile => never hoisted; only loads stay as asm) ----
#define SLOAD4(d0, d1, d2, d3, p, o0, o1, o2, o3) \
    asm volatile("s_load_dwordx16 %0, %4, %5\n\t" \
                 "s_load_dwordx16 %1, %4, %6\n\t" \
                 "s_load_dwordx16 %2, %4, %7\n\t" \
                 "s_load_dwordx16 %3, %4, %8\n\t" \
                 "s_waitcnt lgkmcnt(0)" \
                 : "=&s"(d0), "=&s"(d1), "=&s"(d2), "=&s"(d3) \
                 : "s"(p), "i"(o0), "i"(o1), "i"(o2), "i"(o3));

#define SLD16(d, obytes, p) \
    asm volatile("s_load_dwordx16 %0, %1, %2\n\t" \
                 "s_waitcnt lgkmcnt(0)" \
                 : "=&s"(d) : "s"(p), "i"(obytes));

#define SLOADX8(d0, p) \
    asm volatile("s_load_dwordx8 %0, %1, 0\n\t" \
                 "s_waitcnt lgkmcnt(0)" \
                 : "=&s"(d0) : "s"(p));

// ---- LDS uniform batched read (proven): 4 x b128, wait inside ----
#define LDS4U(A, B, C, D, ADDR) \
    asm volatile("ds_read_b128 %0, %4 offset:0\n\t" \
                 "ds_read_b128 %1, %4 offset:16\n\t" \
                 "ds_read_b128 %2, %4 offset:32\n\t" \
                 "ds_read_b128 %3, %4 offset:48\n\t" \
                 "s_waitcnt lgkmcnt(0)" \
                 : "=&v"(A), "=&v"(B), "=&v"(C), "=&v"(D) : "v"(ADDR));

// ---- pair extracts (plain values; compiler folds into VOP3P operands) ----
#define PKW(W, e)   __builtin_shufflevector((W), (W), 2*(e), 2*(e)+1)   // f16s -> f2
#define SHF2(V, h_) __builtin_shufflevector((V), (V), 2*(h_), 2*(h_)+1) // f4  -> f2

// ---- plain C packed math (clang -> v_pk_fma_f32 etc. on gfx950) ----
#define PKFMA_ACC(acc, w2, m2)      (acc) = __builtin_elementwise_fma((w2), (m2), (acc));
#define PKFMA_NEW(dst, w2, m2, c2)  (dst) = __builtin_elementwise_fma((w2), (m2), (c2));

#define PKROW_E(e, arr, base, m2v, W) PKFMA_ACC((arr)[(base)+(e)], PKW(W, e), m2v)
#define PKROW(arr, m2v, wa, wb, wc, wd) \
    AP8(PKROW_E, arr, 0,  m2v, wa) AP8(PKROW_E, arr, 8,  m2v, wb) \
    AP8(PKROW_E, arr, 16, m2v, wc) AP8(PKROW_E, arr, 24, m2v, wd)

// out-matmul: acc2 += owT-pair * xe2[pair]
#define OPK_E(e, acc, base, W) PKFMA_ACC(acc, PKW(W, e), xe2[(base)+(e)])

__global__ void transpose_ow_kernel(const float* __restrict__ ow,
                                    float* __restrict__ owt) {
    int t = threadIdx.x;
    if (t < HID * SD) owt[(t % SD) * HID + (t / SD)] = ow[t];   // owT[i][j]
}

__global__ __launch_bounds__(256) __attribute__((amdgpu_waves_per_eu(2)))
void strange_loop_kernel(const float* __restrict__ s7,
                         const float* __restrict__ w0,
                         const float* __restrict__ b0,
                         const float* __restrict__ lns,
                         const float* __restrict__ lnb,
                         const float* __restrict__ owt,
                         const float* __restrict__ ob,
                         float* __restrict__ out_mu,
                         float* __restrict__ out_cv,
                         int Bn)
{
    __shared__ __align__(16) float lnp[HID];     // lnb staged in LDS (VGPR source)
    const int tid = threadIdx.x;
    if (tid < HID) lnp[tid] = lnb[tid];
    __syncthreads();

    const unsigned alnb = (unsigned)(size_t)(&lnp[0]);
    const unsigned aln0 = alnb, aln1 = alnb + 64, aln2 = alnb + 128, aln3 = alnb + 192;

    int row = blockIdx.x * blockDim.x + tid;
    if (row >= Bn) row = Bn - 1;   // clamp: uniform control flow, dup write benign

    float s[SD];
#define LD_S(k) s[k] = s7[(size_t)row * SD + (k)];
    REP7(LD_S)

    // ---- iteration-invariant: Be2 = b0 + sum_k s[k]*W0[7+k][.] (packed pairs) ----
    f2 Be2[32];
    {
        f16s ba, bb, bc, bd;
        SLOAD4(ba, bb, bc, bd, b0, 0, 64, 128, 192)
#define B0P(e, W, base) Be2[(base)+(e)] = PKW(W, e);
        AP8(B0P, ba, 0) AP8(B0P, bb, 8) AP8(B0P, bc, 16) AP8(B0P, bd, 24)
    }
#define BIK(k) { f16s wa, wb, wc, wd; \
    SLOAD4(wa, wb, wc, wd, w0, (7+(k))*256, (7+(k))*256+64, (7+(k))*256+128, (7+(k))*256+192) \
    f2 m2 = {s[k], s[k]}; \
    PKROW(Be2, m2, wa, wb, wc, wd) }
    REP7(BIK)

    f8s obv;
    SLOADX8(obv, ob)

    float mu[SD];
#define INITMU(i) mu[i] = 0.37796447300922720f;   // 1/sqrt(7)
    REP7(INITMU)
    float conv = 0.0f;

#pragma unroll 1
    for (int it = 0; it < NITER; ++it) {
        // ---- fc0 packed: xe2 = Be2 + sum_k mu[k]*W0[k][.]; k=0 writes fresh ----
        f2 xe2[32];
        { f16s wa, wb, wc, wd;
          SLOAD4(wa, wb, wc, wd, w0, 0, 64, 128, 192)
          f2 m2 = {mu[0], mu[0]};
#define FC00_E(e, W, base) PKFMA_NEW(xe2[(base)+(e)], PKW(W, e), m2, Be2[(base)+(e)])
          AP8(FC00_E, wa, 0) AP8(FC00_E, wb, 8) AP8(FC00_E, wc, 16) AP8(FC00_E, wd, 24)
        }
#define FC0K(k) { f16s wa, wb, wc, wd; \
        SLOAD4(wa, wb, wc, wd, w0, (k)*256, (k)*256+64, (k)*256+128, (k)*256+192) \
        f2 m2 = {mu[k], mu[k]}; \
        PKROW(xe2, m2, wa, wb, wc, wd) }
        FC0K(1) FC0K(2) FC0K(3) FC0K(4) FC0K(5) FC0K(6)

        // ---- LayerNorm (packed two-pass, same chains as r12) ----
        f2 P01 = xe2[0], P23 = xe2[1];
#define SACE(q) P01 += xe2[2*(q)]; P23 += xe2[2*(q)+1];
        REP15(SACE)
        float mean = ((P01.x + P01.y) + (P23.x + P23.y)) * (1.0f / HID);

        f2 V01 = {0.f, 0.f}, V23 = {0.f, 0.f};
        {
            f2 mn2 = {mean, mean};
#define VACE(q) { f2 a0 = xe2[2*(q)] - mn2; f2 a1 = xe2[2*(q)+1] - mn2; \
            V01 = __builtin_elementwise_fma(a0, a0, V01); \
            V23 = __builtin_elementwise_fma(a1, a1, V23); \
            xe2[2*(q)] = a0; xe2[2*(q)+1] = a1; }
            REP16(VACE)
        }
        float var  = ((V01.x + V01.y) + (V23.x + V23.y)) * (1.0f / HID);
        float rstd = 1.0f / sqrtf(var + 1e-6f);

        // ---- scale/shift + GELU (r12 arithmetic, plain C packed) ----
        {
            const f2 rs2 = {rstd, rstd};
            const f2 kB2 = {0.044715f, 0.044715f};
            const f2 kC2 = {-1.5957691216057308f, -1.5957691216057308f};
#define GEL1(p, lss, lbv) { \
            f2 t = xe2[p] * rs2; \
            f2 g = __builtin_elementwise_fma(t, lss, lbv); \
            f2 g2 = g * g; f2 g3 = g2 * g; \
            f2 z = __builtin_elementwise_fma(kB2, g3, g) * kC2; \
            float e0 = __expf(z.x), e1 = __expf(z.y); \
            xe2[p].x = __fdividef(g.x, 1.0f + e0); \
            xe2[p].y = __fdividef(g.y, 1.0f + e1); }
#define GELH(h, AH) { f16s lsg; SLD16(lsg, (h)*64, lns) \
            f4 L0, L1, L2, L3; LDS4U(L0, L1, L2, L3, AH) \
            GEL1(8*(h)+0, PKW(lsg,0), SHF2(L0,0)) \
            GEL1(8*(h)+1, PKW(lsg,1), SHF2(L0,1)) \
            GEL1(8*(h)+2, PKW(lsg,2), SHF2(L1,0)) \
            GEL1(8*(h)+3, PKW(lsg,3), SHF2(L1,1)) \
            GEL1(8*(h)+4, PKW(lsg,4), SHF2(L2,0)) \
            GEL1(8*(h)+5, PKW(lsg,5), SHF2(L2,1)) \
            GEL1(8*(h)+6, PKW(lsg,6), SHF2(L3,0)) \
            GEL1(8*(h)+7, PKW(lsg,7), SHF2(L3,1)) }
            GELH(0, aln0) GELH(1, aln1) GELH(2, aln2) GELH(3, aln3)
        }

        // ---- out matmul packed: u[i] = sum_p owT[i].pair(p) * xe2[p] ----
        float u[SD];
#define OUTI(i) { f16s wa, wb, wc, wd; \
        SLOAD4(wa, wb, wc, wd, owt, (i)*256, (i)*256+64, (i)*256+128, (i)*256+192) \
        f2 acc = {0.f, 0.f}; \
        AP8(OPK_E, acc, 0,  wa) AP8(OPK_E, acc, 8,  wb) \
        AP8(OPK_E, acc, 16, wc) AP8(OPK_E, acc, 24, wd) \
        u[i] = (acc.x + acc.y) + obv[i]; }
        REP7(OUTI)

        // ---- L2 normalize (identical) ----
        float ss = 0.f;
#define SSQ(i) ss = fmaf(u[i], u[i], ss);
        REP7(SSQ)
        float inv = __fdividef(1.0f, sqrtf(ss) + 1e-8f);

        // ---- damped update + convergence (identical) ----
        float dd = 0.f;
#define UPD(i) { float un = u[i] * inv; float mn = 0.5f * mu[i] + 0.5f * un; \
        float d = mn - mu[i]; dd = fmaf(d, d, dd); mu[i] = mn; }
        REP7(UPD)
        if (sqrtf(dd) < 1e-4f) conv = 1.0f;
    }

#define ST(i) out_mu[(size_t)row * SD + (i)] = mu[i];
    REP7(ST)
    out_cv[row] = conv;
}

extern "C" void kernel_launch(void* const* d_in, const int* in_sizes, int n_in,
                              void* d_out, int out_size, void* d_ws, size_t ws_size,
                              hipStream_t stream) {
    const float* s7  = (const float*)d_in[0];
    const float* w0  = (const float*)d_in[1];
    const float* b0  = (const float*)d_in[2];
    const float* lns = (const float*)d_in[3];
    const float* lnb = (const float*)d_in[4];
    const float* ow  = (const float*)d_in[5];
    const float* ob  = (const float*)d_in[6];
    const int Bn = in_sizes[0] / SD;

    float* out_mu = (float*)d_out;
    float* out_cv = out_mu + (size_t)Bn * SD;
    float* owt    = (float*)d_ws;            // 448 floats = 1792 B scratch

    hipLaunchKernelGGL(transpose_ow_kernel, dim3(1), dim3(512), 0, stream, ow, owt);

    const int block = 256;
    const int grid  = (Bn + block - 1) / block;
    hipLaunchKernelGGL(strange_loop_kernel, dim3(grid), dim3(block), 0, stream,
                       s7, w0, b0, lns, lnb, owt, ob, out_mu, out_cv, Bn);
}

// Round 17
// 548.357 us; speedup vs baseline: 1.2647x; 1.0734x over previous
//
#include <hip/hip_runtime.h>
#include <math.h>

#define SD 7
#define HID 64
#define NITER 10

typedef float f16s __attribute__((ext_vector_type(16)));
typedef float f8s  __attribute__((ext_vector_type(8)));
typedef float f2   __attribute__((ext_vector_type(2)));

#define REP7(M)  M(0) M(1) M(2) M(3) M(4) M(5) M(6)
#define REP15(M) M(1) M(2) M(3) M(4) M(5) M(6) M(7) M(8) M(9) M(10) M(11) M(12) M(13) M(14) M(15)
#define REP16(M) M(0) M(1) M(2) M(3) M(4) M(5) M(6) M(7) M(8) M(9) M(10) M(11) M(12) M(13) M(14) M(15)
#define AP8(M, ...) M(0, __VA_ARGS__) M(1, __VA_ARGS__) M(2, __VA_ARGS__) M(3, __VA_ARGS__) \
    M(4, __VA_ARGS__) M(5, __VA_ARGS__) M(6, __VA_ARGS__) M(7, __VA_ARGS__)

// ---- SMEM loads (volatile => never hoisted) ----
#define SLOAD4(d0, d1, d2, d3, p, o0, o1, o2, o3) \
    asm volatile("s_load_dwordx16 %0, %4, %5\n\t" \
                 "s_load_dwordx16 %1, %4, %6\n\t" \
                 "s_load_dwordx16 %2, %4, %7\n\t" \
                 "s_load_dwordx16 %3, %4, %8\n\t" \
                 "s_waitcnt lgkmcnt(0)" \
                 : "=&s"(d0), "=&s"(d1), "=&s"(d2), "=&s"(d3) \
                 : "s"(p), "i"(o0), "i"(o1), "i"(o2), "i"(o3));

#define SLOADX8(d0, p) \
    asm volatile("s_load_dwordx8 %0, %1, 0\n\t" \
                 "s_waitcnt lgkmcnt(0)" \
                 : "=&s"(d0) : "s"(p));

// ---- pair extracts (plain values; fold into VOP3P scalar operand) ----
#define PKW(W, e)   __builtin_shufflevector((W), (W), 2*(e), 2*(e)+1)   // f16s -> f2

// ---- plain C packed math (clang -> v_pk_* on gfx950) ----
#define PKFMA_ACC(acc, w2, m2)      (acc) = __builtin_elementwise_fma((w2), (m2), (acc));
#define PKFMA_NEW(dst, w2, m2, c2)  (dst) = __builtin_elementwise_fma((w2), (m2), (c2));

#define PKROW_E(e, arr, base, m2v, W) PKFMA_ACC((arr)[(base)+(e)], PKW(W, e), m2v)
#define PKROW(arr, m2v, wa, wb, wc, wd) \
    AP8(PKROW_E, arr, 0,  m2v, wa) AP8(PKROW_E, arr, 8,  m2v, wb) \
    AP8(PKROW_E, arr, 16, m2v, wc) AP8(PKROW_E, arr, 24, m2v, wd)

// out-matmul: acc2 += owT-pair * xe2[pair]
#define OPK_E(e, acc, base, W) PKFMA_ACC(acc, PKW(W, e), xe2[(base)+(e)])

// prep: owT[7][64] transpose + interleaved ln params {ls0,ls1,lb0,lb1,...}
__global__ void prep_kernel(const float* __restrict__ ow,
                            const float* __restrict__ lns,
                            const float* __restrict__ lnb,
                            float* __restrict__ ws) {
    int t = threadIdx.x;
    if (t < HID * SD) {
        ws[(t % SD) * HID + (t / SD)] = ow[t];            // owT[i][j]
    } else if (t < HID * SD + 2 * HID) {
        int i = t - HID * SD;                             // 0..127
        int p = i >> 2, r = i & 3;
        ws[HID * SD + i] = (r < 2) ? lns[2 * p + r] : lnb[2 * p + (r - 2)];
    }
}

__global__ __launch_bounds__(256) __attribute__((amdgpu_waves_per_eu(3, 3)))
void strange_loop_kernel(const float* __restrict__ s7,
                         const float* __restrict__ w0,
                         const float* __restrict__ b0,
                         const float* __restrict__ owt,
                         const float* __restrict__ lsb,
                         const float* __restrict__ ob,
                         float* __restrict__ out_mu,
                         float* __restrict__ out_cv,
                         int Bn)
{
    const int tid = threadIdx.x;
    int row = blockIdx.x * blockDim.x + tid;
    if (row >= Bn) row = Bn - 1;   // clamp: uniform control flow, dup write benign

    float s[SD];
#define LD_S(k) s[k] = s7[(size_t)row * SD + (k)];
    REP7(LD_S)

    // ---- iteration-invariant: Be2 = b0 + sum_k s[k]*W0[7+k][.] (packed pairs) ----
    f2 Be2[32];
    {
        f16s ba, bb, bc, bd;
        SLOAD4(ba, bb, bc, bd, b0, 0, 64, 128, 192)
#define B0P(e, W, base) Be2[(base)+(e)] = PKW(W, e);
        AP8(B0P, ba, 0) AP8(B0P, bb, 8) AP8(B0P, bc, 16) AP8(B0P, bd, 24)
    }
#define BIK(k) { f16s wa, wb, wc, wd; \
    SLOAD4(wa, wb, wc, wd, w0, (7+(k))*256, (7+(k))*256+64, (7+(k))*256+128, (7+(k))*256+192) \
    f2 m2 = {s[k], s[k]}; \
    PKROW(Be2, m2, wa, wb, wc, wd) }
    REP7(BIK)

    f8s obv;
    SLOADX8(obv, ob)

    float mu[SD];
#define INITMU(i) mu[i] = 0.37796447300922720f;   // 1/sqrt(7)
    REP7(INITMU)
    float conv = 0.0f;

#pragma unroll 1
    for (int it = 0; it < NITER; ++it) {
        // ---- fc0 packed: xe2 = Be2 + sum_k mu[k]*W0[k][.]; k=0 writes fresh ----
        f2 xe2[32];
        { f16s wa, wb, wc, wd;
          SLOAD4(wa, wb, wc, wd, w0, 0, 64, 128, 192)
          f2 m2 = {mu[0], mu[0]};
#define FC00_E(e, W, base) PKFMA_NEW(xe2[(base)+(e)], PKW(W, e), m2, Be2[(base)+(e)])
          AP8(FC00_E, wa, 0) AP8(FC00_E, wb, 8) AP8(FC00_E, wc, 16) AP8(FC00_E, wd, 24)
        }
#define FC0K(k) { f16s wa, wb, wc, wd; \
        SLOAD4(wa, wb, wc, wd, w0, (k)*256, (k)*256+64, (k)*256+128, (k)*256+192) \
        f2 m2 = {mu[k], mu[k]}; \
        PKROW(xe2, m2, wa, wb, wc, wd) }
        FC0K(1) FC0K(2) FC0K(3) FC0K(4) FC0K(5) FC0K(6)

        // ---- LayerNorm (packed two-pass, same chains as r12/r15) ----
        f2 P01 = xe2[0], P23 = xe2[1];
#define SACE(q) P01 += xe2[2*(q)]; P23 += xe2[2*(q)+1];
        REP15(SACE)
        float mean = ((P01.x + P01.y) + (P23.x + P23.y)) * (1.0f / HID);

        f2 V01 = {0.f, 0.f}, V23 = {0.f, 0.f};
        {
            f2 mn2 = {mean, mean};
#define VACE(q) { f2 a0 = xe2[2*(q)] - mn2; f2 a1 = xe2[2*(q)+1] - mn2; \
            V01 = __builtin_elementwise_fma(a0, a0, V01); \
            V23 = __builtin_elementwise_fma(a1, a1, V23); \
            xe2[2*(q)] = a0; xe2[2*(q)+1] = a1; }
            REP16(VACE)
        }
        float var  = ((V01.x + V01.y) + (V23.x + V23.y)) * (1.0f / HID);
        float rstd = 1.0f / sqrtf(var + 1e-6f);

        // ---- scale/shift + GELU; params interleaved from SMEM (2 groups) ----
        {
            const f2 rs2 = {rstd, rstd};
            const f2 kB2 = {0.044715f, 0.044715f};
            const f2 kC2 = {-1.5957691216057308f, -1.5957691216057308f};
#define GEL1(p, lsS, lbS) { \
            f2 t = xe2[p] * rs2; \
            f2 g = t * (lsS); \
            g = g + (lbS); \
            f2 g2 = g * g; f2 g3 = g2 * g; \
            f2 z = __builtin_elementwise_fma(kB2, g3, g) * kC2; \
            float e0 = __expf(z.x), e1 = __expf(z.y); \
            xe2[p].x = __fdividef(g.x, 1.0f + e0); \
            xe2[p].y = __fdividef(g.y, 1.0f + e1); }
#define GELT(W, pb) \
            GEL1((pb)+0, PKW(W,0), PKW(W,1)) \
            GEL1((pb)+1, PKW(W,2), PKW(W,3)) \
            GEL1((pb)+2, PKW(W,4), PKW(W,5)) \
            GEL1((pb)+3, PKW(W,6), PKW(W,7))
#define GELG(h) { f16s wa, wb, wc, wd; \
            SLOAD4(wa, wb, wc, wd, lsb, (h)*256, (h)*256+64, (h)*256+128, (h)*256+192) \
            GELT(wa, 16*(h)+0) GELT(wb, 16*(h)+4) \
            GELT(wc, 16*(h)+8) GELT(wd, 16*(h)+12) }
            GELG(0) GELG(1)
        }

        // ---- out matmul packed: u[i] = sum_p owT[i].pair(p) * xe2[p] ----
        float u[SD];
#define OUTI(i) { f16s wa, wb, wc, wd; \
        SLOAD4(wa, wb, wc, wd, owt, (i)*256, (i)*256+64, (i)*256+128, (i)*256+192) \
        f2 acc = {0.f, 0.f}; \
        AP8(OPK_E, acc, 0,  wa) AP8(OPK_E, acc, 8,  wb) \
        AP8(OPK_E, acc, 16, wc) AP8(OPK_E, acc, 24, wd) \
        u[i] = (acc.x + acc.y) + obv[i]; }
        REP7(OUTI)

        // ---- L2 normalize (identical) ----
        float ss = 0.f;
#define SSQ(i) ss = fmaf(u[i], u[i], ss);
        REP7(SSQ)
        float inv = __fdividef(1.0f, sqrtf(ss) + 1e-8f);

        // ---- damped update + convergence (identical) ----
        float dd = 0.f;
#define UPD(i) { float un = u[i] * inv; float mn = 0.5f * mu[i] + 0.5f * un; \
        float d = mn - mu[i]; dd = fmaf(d, d, dd); mu[i] = mn; }
        REP7(UPD)
        if (sqrtf(dd) < 1e-4f) conv = 1.0f;
    }

#define ST(i) out_mu[(size_t)row * SD + (i)] = mu[i];
    REP7(ST)
    out_cv[row] = conv;
}

extern "C" void kernel_launch(void* const* d_in, const int* in_sizes, int n_in,
                              void* d_out, int out_size, void* d_ws, size_t ws_size,
                              hipStream_t stream) {
    const float* s7  = (const float*)d_in[0];
    const float* w0  = (const float*)d_in[1];
    const float* b0  = (const float*)d_in[2];
    const float* lns = (const float*)d_in[3];
    const float* lnb = (const float*)d_in[4];
    const float* ow  = (const float*)d_in[5];
    const float* ob  = (const float*)d_in[6];
    const int Bn = in_sizes[0] / SD;

    float* out_mu = (float*)d_out;
    float* out_cv = out_mu + (size_t)Bn * SD;
    float* ws     = (float*)d_ws;            // owt[448] | lsbI[128]
    float* owt    = ws;
    float* lsb    = ws + HID * SD;

    hipLaunchKernelGGL(prep_kernel, dim3(1), dim3(640), 0, stream, ow, lns, lnb, ws);

    const int block = 256;
    const int grid  = (Bn + block - 1) / block;
    hipLaunchKernelGGL(strange_loop_kernel, dim3(grid), dim3(block), 0, stream,
                       s7, w0, b0, owt, lsb, ob, out_mu, out_cv, Bn);
}

// Round 18
// 517.037 us; speedup vs baseline: 1.3413x; 1.0606x over previous
//
#include <hip/hip_runtime.h>
#include <math.h>

#define SD 7
#define HID 64
#define NITER 10

typedef float f16s __attribute__((ext_vector_type(16)));
typedef float f8s  __attribute__((ext_vector_type(8)));
typedef float f2   __attribute__((ext_vector_type(2)));

#define REP7(M)  M(0) M(1) M(2) M(3) M(4) M(5) M(6)
#define REP15(M) M(1) M(2) M(3) M(4) M(5) M(6) M(7) M(8) M(9) M(10) M(11) M(12) M(13) M(14) M(15)
#define REP16(M) M(0) M(1) M(2) M(3) M(4) M(5) M(6) M(7) M(8) M(9) M(10) M(11) M(12) M(13) M(14) M(15)
#define AP8(M, ...) M(0, __VA_ARGS__) M(1, __VA_ARGS__) M(2, __VA_ARGS__) M(3, __VA_ARGS__) \
    M(4, __VA_ARGS__) M(5, __VA_ARGS__) M(6, __VA_ARGS__) M(7, __VA_ARGS__)

// ---- SMEM loads (volatile => never hoisted) ----
#define SLOAD4(d0, d1, d2, d3, p, o0, o1, o2, o3) \
    asm volatile("s_load_dwordx16 %0, %4, %5\n\t" \
                 "s_load_dwordx16 %1, %4, %6\n\t" \
                 "s_load_dwordx16 %2, %4, %7\n\t" \
                 "s_load_dwordx16 %3, %4, %8\n\t" \
                 "s_waitcnt lgkmcnt(0)" \
                 : "=&s"(d0), "=&s"(d1), "=&s"(d2), "=&s"(d3) \
                 : "s"(p), "i"(o0), "i"(o1), "i"(o2), "i"(o3));

#define SLOADX8(d0, p) \
    asm volatile("s_load_dwordx8 %0, %1, 0\n\t" \
                 "s_waitcnt lgkmcnt(0)" \
                 : "=&s"(d0) : "s"(p));

// ---- pair extracts (plain values; fold into VOP3P scalar operand) ----
#define PKW(W, e)   __builtin_shufflevector((W), (W), 2*(e), 2*(e)+1)   // f16s -> f2

// ---- plain C packed math (clang -> v_pk_* on gfx950) ----
#define PKFMA_ACC(acc, w2, m2)      (acc) = __builtin_elementwise_fma((w2), (m2), (acc));
#define PKFMA_NEW(dst, w2, m2, c2)  (dst) = __builtin_elementwise_fma((w2), (m2), (c2));

#define PKROW_E(e, arr, base, m2v, W) PKFMA_ACC((arr)[(base)+(e)], PKW(W, e), m2v)
#define PKROW(arr, m2v, wa, wb, wc, wd) \
    AP8(PKROW_E, arr, 0,  m2v, wa) AP8(PKROW_E, arr, 8,  m2v, wb) \
    AP8(PKROW_E, arr, 16, m2v, wc) AP8(PKROW_E, arr, 24, m2v, wd)

// out-matmul: acc2 += owT-pair * xe2[pair]
#define OPK_E(e, acc, base, W) PKFMA_ACC(acc, PKW(W, e), xe2[(base)+(e)])

// prep: owT[7][64] transpose + interleaved ln params {ls0,ls1,lb0,lb1,...}
__global__ void prep_kernel(const float* __restrict__ ow,
                            const float* __restrict__ lns,
                            const float* __restrict__ lnb,
                            float* __restrict__ ws) {
    int t = threadIdx.x;
    if (t < HID * SD) {
        ws[(t % SD) * HID + (t / SD)] = ow[t];            // owT[i][j]
    } else if (t < HID * SD + 2 * HID) {
        int i = t - HID * SD;                             // 0..127
        int p = i >> 2, r = i & 3;
        ws[HID * SD + i] = (r < 2) ? lns[2 * p + r] : lnb[2 * p + (r - 2)];
    }
}

__global__ __launch_bounds__(256) __attribute__((amdgpu_waves_per_eu(3, 3)))
void strange_loop_kernel(const float* __restrict__ s7,
                         const float* __restrict__ w0,
                         const float* __restrict__ b0,
                         const float* __restrict__ owt,
                         const float* __restrict__ lsb,
                         const float* __restrict__ ob,
                         float* __restrict__ out_mu,
                         float* __restrict__ out_cv,
                         int Bn)
{
    const int tid = threadIdx.x;
    int row = blockIdx.x * blockDim.x + tid;
    if (row >= Bn) row = Bn - 1;   // clamp: uniform control flow, dup write benign

    float s[SD];
#define LD_S(k) s[k] = s7[(size_t)row * SD + (k)];
    REP7(LD_S)

    // ---- iteration-invariant: Be2 = b0 + sum_k s[k]*W0[7+k][.] (packed pairs) ----
    f2 Be2[32];
    {
        f16s ba, bb, bc, bd;
        SLOAD4(ba, bb, bc, bd, b0, 0, 64, 128, 192)
#define B0P(e, W, base) Be2[(base)+(e)] = PKW(W, e);
        AP8(B0P, ba, 0) AP8(B0P, bb, 8) AP8(B0P, bc, 16) AP8(B0P, bd, 24)
    }
#define BIK(k) { f16s wa, wb, wc, wd; \
    SLOAD4(wa, wb, wc, wd, w0, (7+(k))*256, (7+(k))*256+64, (7+(k))*256+128, (7+(k))*256+192) \
    f2 m2 = {s[k], s[k]}; \
    PKROW(Be2, m2, wa, wb, wc, wd) }
    REP7(BIK)

    f8s obv;
    SLOADX8(obv, ob)

    float mu[SD];
#define INITMU(i) mu[i] = 0.37796447300922720f;   // 1/sqrt(7)
    REP7(INITMU)
    float conv = 0.0f;

    // GELU constants, log2e pre-folded (double-folded at compile time):
    // e^(kC*(g + kB g^3)) == 2^( g * (kCl + kBCl*g^2) )
    const double kCd  = -1.5957691216057308 * 1.4426950408889634;
    const float  kCl  = (float)kCd;
    const float  kBCl = (float)(kCd * 0.044715);

#pragma unroll 1
    for (int it = 0; it < NITER; ++it) {
        // ---- fc0 packed: xe2 = Be2 + sum_k mu[k]*W0[k][.]; k=0 writes fresh ----
        f2 xe2[32];
        { f16s wa, wb, wc, wd;
          SLOAD4(wa, wb, wc, wd, w0, 0, 64, 128, 192)
          f2 m2 = {mu[0], mu[0]};
#define FC00_E(e, W, base) PKFMA_NEW(xe2[(base)+(e)], PKW(W, e), m2, Be2[(base)+(e)])
          AP8(FC00_E, wa, 0) AP8(FC00_E, wb, 8) AP8(FC00_E, wc, 16) AP8(FC00_E, wd, 24)
        }
#define FC0K(k) { f16s wa, wb, wc, wd; \
        SLOAD4(wa, wb, wc, wd, w0, (k)*256, (k)*256+64, (k)*256+128, (k)*256+192) \
        f2 m2 = {mu[k], mu[k]}; \
        PKROW(xe2, m2, wa, wb, wc, wd) }
        FC0K(1) FC0K(2) FC0K(3) FC0K(4) FC0K(5) FC0K(6)

        // ---- LayerNorm (packed two-pass, same chains as r12/r15/r16) ----
        f2 P01 = xe2[0], P23 = xe2[1];
#define SACE(q) P01 += xe2[2*(q)]; P23 += xe2[2*(q)+1];
        REP15(SACE)
        float mean = ((P01.x + P01.y) + (P23.x + P23.y)) * (1.0f / HID);

        f2 V01 = {0.f, 0.f}, V23 = {0.f, 0.f};
        {
            f2 mn2 = {mean, mean};
#define VACE(q) { f2 a0 = xe2[2*(q)] - mn2; f2 a1 = xe2[2*(q)+1] - mn2; \
            V01 = __builtin_elementwise_fma(a0, a0, V01); \
            V23 = __builtin_elementwise_fma(a1, a1, V23); \
            xe2[2*(q)] = a0; xe2[2*(q)+1] = a1; }
            REP16(VACE)
        }
        float var  = ((V01.x + V01.y) + (V23.x + V23.y)) * (1.0f / HID);
        float rstd = __builtin_amdgcn_rsqf(var + 1e-6f);    // 1-ulp rsqrt, 1 inst

        // ---- scale/shift + GELU; params interleaved from SMEM (2 groups) ----
        {
            const f2 rs2  = {rstd, rstd};
            const f2 kBC2 = {kBCl, kBCl};
            const f2 kC2n = {kCl, kCl};
#define GEL1(p, lsS, lbS) { \
            f2 t = xe2[p] * rs2; \
            f2 g = t * (lsS); \
            g = g + (lbS); \
            f2 g2 = g * g; \
            f2 inner = __builtin_elementwise_fma(g2, kBC2, kC2n); \
            f2 z = g * inner; \
            float e0 = __builtin_amdgcn_exp2f(z.x); \
            float e1 = __builtin_amdgcn_exp2f(z.y); \
            xe2[p].x = __fdividef(g.x, 1.0f + e0); \
            xe2[p].y = __fdividef(g.y, 1.0f + e1); }
#define GELT(W, pb) \
            GEL1((pb)+0, PKW(W,0), PKW(W,1)) \
            GEL1((pb)+1, PKW(W,2), PKW(W,3)) \
            GEL1((pb)+2, PKW(W,4), PKW(W,5)) \
            GEL1((pb)+3, PKW(W,6), PKW(W,7))
#define GELG(h) { f16s wa, wb, wc, wd; \
            SLOAD4(wa, wb, wc, wd, lsb, (h)*256, (h)*256+64, (h)*256+128, (h)*256+192) \
            GELT(wa, 16*(h)+0) GELT(wb, 16*(h)+4) \
            GELT(wc, 16*(h)+8) GELT(wd, 16*(h)+12) }
            GELG(0) GELG(1)
        }

        // ---- out matmul packed: u[i] = sum_p owT[i].pair(p) * xe2[p] ----
        float u[SD];
#define OUTI(i) { f16s wa, wb, wc, wd; \
        SLOAD4(wa, wb, wc, wd, owt, (i)*256, (i)*256+64, (i)*256+128, (i)*256+192) \
        f2 acc = {0.f, 0.f}; \
        AP8(OPK_E, acc, 0,  wa) AP8(OPK_E, acc, 8,  wb) \
        AP8(OPK_E, acc, 16, wc) AP8(OPK_E, acc, 24, wd) \
        u[i] = (acc.x + acc.y) + obv[i]; }
        REP7(OUTI)

        // ---- L2 normalize (single-inst sqrt; div path unchanged) ----
        float ss = 0.f;
#define SSQ(i) ss = fmaf(u[i], u[i], ss);
        REP7(SSQ)
        float inv = __fdividef(1.0f, __builtin_amdgcn_sqrtf(ss) + 1e-8f);

        // ---- damped update + convergence (exact sqrtf kept for the flag) ----
        float dd = 0.f;
#define UPD(i) { float un = u[i] * inv; float mn = 0.5f * mu[i] + 0.5f * un; \
        float d = mn - mu[i]; dd = fmaf(d, d, dd); mu[i] = mn; }
        REP7(UPD)
        if (sqrtf(dd) < 1e-4f) conv = 1.0f;
    }

#define ST(i) out_mu[(size_t)row * SD + (i)] = mu[i];
    REP7(ST)
    out_cv[row] = conv;
}

extern "C" void kernel_launch(void* const* d_in, const int* in_sizes, int n_in,
                              void* d_out, int out_size, void* d_ws, size_t ws_size,
                              hipStream_t stream) {
    const float* s7  = (const float*)d_in[0];
    const float* w0  = (const float*)d_in[1];
    const float* b0  = (const float*)d_in[2];
    const float* lns = (const float*)d_in[3];
    const float* lnb = (const float*)d_in[4];
    const float* ow  = (const float*)d_in[5];
    const float* ob  = (const float*)d_in[6];
    const int Bn = in_sizes[0] / SD;

    float* out_mu = (float*)d_out;
    float* out_cv = out_mu + (size_t)Bn * SD;
    float* ws     = (float*)d_ws;            // owt[448] | lsbI[128]
    float* owt    = ws;
    float* lsb    = ws + HID * SD;

    hipLaunchKernelGGL(prep_kernel, dim3(1), dim3(640), 0, stream, ow, lns, lnb, ws);

    const int block = 256;
    const int grid  = (Bn + block - 1) / block;
    hipLaunchKernelGGL(strange_loop_kernel, dim3(grid), dim3(block), 0, stream,
                       s7, w0, b0, owt, lsb, ob, out_mu, out_cv, Bn);
}

// Round 19
// 353.481 us; speedup vs baseline: 1.9619x; 1.4627x over previous
//
#include <hip/hip_runtime.h>
#include <math.h>

#define SD 7
#define HID 64
#define NITER 10

typedef float f16s __attribute__((ext_vector_type(16)));
typedef float f8s  __attribute__((ext_vector_type(8)));
typedef float f2   __attribute__((ext_vector_type(2)));

#define REP7(M)  M(0) M(1) M(2) M(3) M(4) M(5) M(6)
#define REP15(M) M(1) M(2) M(3) M(4) M(5) M(6) M(7) M(8) M(9) M(10) M(11) M(12) M(13) M(14) M(15)
#define AP8(M, ...) M(0, __VA_ARGS__) M(1, __VA_ARGS__) M(2, __VA_ARGS__) M(3, __VA_ARGS__) \
    M(4, __VA_ARGS__) M(5, __VA_ARGS__) M(6, __VA_ARGS__) M(7, __VA_ARGS__)

// ---- SMEM loads (volatile => never hoisted) ----
#define SLOAD4(d0, d1, d2, d3, p, o0, o1, o2, o3) \
    asm volatile("s_load_dwordx16 %0, %4, %5\n\t" \
                 "s_load_dwordx16 %1, %4, %6\n\t" \
                 "s_load_dwordx16 %2, %4, %7\n\t" \
                 "s_load_dwordx16 %3, %4, %8\n\t" \
                 "s_waitcnt lgkmcnt(0)" \
                 : "=&s"(d0), "=&s"(d1), "=&s"(d2), "=&s"(d3) \
                 : "s"(p), "i"(o0), "i"(o1), "i"(o2), "i"(o3));

#define SLOADX8(d0, p) \
    asm volatile("s_load_dwordx8 %0, %1, 0\n\t" \
                 "s_waitcnt lgkmcnt(0)" \
                 : "=&s"(d0) : "s"(p));

// ---- pair extracts (plain values; fold into VOP3P scalar operand) ----
#define PKW(W, e)   __builtin_shufflevector((W), (W), 2*(e), 2*(e)+1)   // f16s -> f2

// ---- plain C packed math (clang -> v_pk_* on gfx950) ----
#define PKFMA_ACC(acc, w2, m2)      (acc) = __builtin_elementwise_fma((w2), (m2), (acc));
#define PKFMA_NEW(dst, w2, m2, c2)  (dst) = __builtin_elementwise_fma((w2), (m2), (c2));

#define PKROW_E(e, arr, base, m2v, W) PKFMA_ACC((arr)[(base)+(e)], PKW(W, e), m2v)
#define PKROW(arr, m2v, wa, wb, wc, wd) \
    AP8(PKROW_E, arr, 0,  m2v, wa) AP8(PKROW_E, arr, 8,  m2v, wb) \
    AP8(PKROW_E, arr, 16, m2v, wc) AP8(PKROW_E, arr, 24, m2v, wd)

// out-matmul: acc2 += owT-pair * xe2[pair]
#define OPK_E(e, acc, base, W) PKFMA_ACC(acc, PKW(W, e), xe2[(base)+(e)])

// prep: owT[7][64] transpose + interleaved ln params {ls0,ls1,lb0,lb1,...}
__global__ void prep_kernel(const float* __restrict__ ow,
                            const float* __restrict__ lns,
                            const float* __restrict__ lnb,
                            float* __restrict__ ws) {
    int t = threadIdx.x;
    if (t < HID * SD) {
        ws[(t % SD) * HID + (t / SD)] = ow[t];            // owT[i][j]
    } else if (t < HID * SD + 2 * HID) {
        int i = t - HID * SD;                             // 0..127
        int p = i >> 2, r = i & 3;
        ws[HID * SD + i] = (r < 2) ? lns[2 * p + r] : lnb[2 * p + (r - 2)];
    }
}

__global__ __launch_bounds__(256) __attribute__((amdgpu_waves_per_eu(3, 3)))
void strange_loop_kernel(const float* __restrict__ s7,
                         const float* __restrict__ w0,
                         const float* __restrict__ b0,
                         const float* __restrict__ owt,
                         const float* __restrict__ lsb,
                         const float* __restrict__ ob,
                         float* __restrict__ out_mu,
                         float* __restrict__ out_cv,
                         int Bn)
{
    const int tid = threadIdx.x;
    int row = blockIdx.x * blockDim.x + tid;
    if (row >= Bn) row = Bn - 1;   // clamp: uniform control flow, dup write benign

    float s[SD];
#define LD_S(k) s[k] = s7[(size_t)row * SD + (k)];
    REP7(LD_S)

    // ---- iteration-invariant: Be2 = b0 + sum_k s[k]*W0[7+k][.] (packed pairs) ----
    f2 Be2[32];
    {
        f16s ba, bb, bc, bd;
        SLOAD4(ba, bb, bc, bd, b0, 0, 64, 128, 192)
#define B0P(e, W, base) Be2[(base)+(e)] = PKW(W, e);
        AP8(B0P, ba, 0) AP8(B0P, bb, 8) AP8(B0P, bc, 16) AP8(B0P, bd, 24)
    }
#define BIK(k) { f16s wa, wb, wc, wd; \
    SLOAD4(wa, wb, wc, wd, w0, (7+(k))*256, (7+(k))*256+64, (7+(k))*256+128, (7+(k))*256+192) \
    f2 m2 = {s[k], s[k]}; \
    PKROW(Be2, m2, wa, wb, wc, wd) }
    REP7(BIK)

    f8s obv;
    SLOADX8(obv, ob)

    float mu[SD];
#define INITMU(i) mu[i] = 0.37796447300922720f;   // 1/sqrt(7)
    REP7(INITMU)
    float conv = 0.0f;

    // GELU constants, log2e pre-folded (double-folded at compile time):
    // e^(kC*(g + kB g^3)) == 2^( g * (kCl + kBCl*g^2) )
    const double kCd  = -1.5957691216057308 * 1.4426950408889634;
    const float  kCl  = (float)kCd;
    const float  kBCl = (float)(kCd * 0.044715);

#pragma unroll 1
    for (int it = 0; it < NITER; ++it) {
        // ---- fc0 packed: xe2 = Be2 + sum_k mu[k]*W0[k][.]; k=0 writes fresh ----
        f2 xe2[32];
        { f16s wa, wb, wc, wd;
          SLOAD4(wa, wb, wc, wd, w0, 0, 64, 128, 192)
          f2 m2 = {mu[0], mu[0]};
#define FC00_E(e, W, base) PKFMA_NEW(xe2[(base)+(e)], PKW(W, e), m2, Be2[(base)+(e)])
          AP8(FC00_E, wa, 0) AP8(FC00_E, wb, 8) AP8(FC00_E, wc, 16) AP8(FC00_E, wd, 24)
        }
#define FC0K(k) { f16s wa, wb, wc, wd; \
        SLOAD4(wa, wb, wc, wd, w0, (k)*256, (k)*256+64, (k)*256+128, (k)*256+192) \
        f2 m2 = {mu[k], mu[k]}; \
        PKROW(xe2, m2, wa, wb, wc, wd) }
        FC0K(1) FC0K(2) FC0K(3) FC0K(4) FC0K(5) FC0K(6)

        // ---- LayerNorm one-pass: mean + E[x^2]; xe2 stays raw ----
        f2 P01 = xe2[0], P23 = xe2[1];
#define SACE(q) P01 += xe2[2*(q)]; P23 += xe2[2*(q)+1];
        REP15(SACE)
        float mean = ((P01.x + P01.y) + (P23.x + P23.y)) * (1.0f / HID);

        f2 Q01 = xe2[0] * xe2[0], Q23 = xe2[1] * xe2[1];
#define QACE(q) { Q01 = __builtin_elementwise_fma(xe2[2*(q)], xe2[2*(q)], Q01); \
                  Q23 = __builtin_elementwise_fma(xe2[2*(q)+1], xe2[2*(q)+1], Q23); }
        REP15(QACE)
        float ms   = ((Q01.x + Q01.y) + (Q23.x + Q23.y)) * (1.0f / HID);
        float var  = fmaf(-mean, mean, ms);                 // E[x^2] - mean^2
        float rstd = __builtin_amdgcn_rsqf(var + 1e-6f);

        // ---- affine-folded scale/shift + GELU (packed sigmoid tail) ----
        {
            const f2 rs2  = {rstd, rstd};
            const f2 mn2n = {-mean, -mean};
            const f2 kBC2 = {kBCl, kBCl};
            const f2 kC2n = {kCl, kCl};
            const f2 one2 = {1.0f, 1.0f};
#define GEL1(p, lsS, lbS) { \
            f2 a = (lsS) * rs2; \
            f2 b = __builtin_elementwise_fma(mn2n, a, (lbS)); \
            f2 g = __builtin_elementwise_fma(xe2[p], a, b); \
            f2 g2 = g * g; \
            f2 inner = __builtin_elementwise_fma(g2, kBC2, kC2n); \
            f2 z = g * inner; \
            f2 e = {__builtin_amdgcn_exp2f(z.x), __builtin_amdgcn_exp2f(z.y)}; \
            f2 d = one2 + e; \
            f2 r = {__builtin_amdgcn_rcpf(d.x), __builtin_amdgcn_rcpf(d.y)}; \
            xe2[p] = g * r; }
#define GELT(W, pb) \
            GEL1((pb)+0, PKW(W,0), PKW(W,1)) \
            GEL1((pb)+1, PKW(W,2), PKW(W,3)) \
            GEL1((pb)+2, PKW(W,4), PKW(W,5)) \
            GEL1((pb)+3, PKW(W,6), PKW(W,7))
#define GELG(h) { f16s wa, wb, wc, wd; \
            SLOAD4(wa, wb, wc, wd, lsb, (h)*256, (h)*256+64, (h)*256+128, (h)*256+192) \
            GELT(wa, 16*(h)+0) GELT(wb, 16*(h)+4) \
            GELT(wc, 16*(h)+8) GELT(wd, 16*(h)+12) }
            GELG(0) GELG(1)
        }

        // ---- out matmul packed: u[i] = sum_p owT[i].pair(p) * xe2[p] ----
        float u[SD];
#define OUTI(i) { f16s wa, wb, wc, wd; \
        SLOAD4(wa, wb, wc, wd, owt, (i)*256, (i)*256+64, (i)*256+128, (i)*256+192) \
        f2 acc = {0.f, 0.f}; \
        AP8(OPK_E, acc, 0,  wa) AP8(OPK_E, acc, 8,  wb) \
        AP8(OPK_E, acc, 16, wc) AP8(OPK_E, acc, 24, wd) \
        u[i] = (acc.x + acc.y) + obv[i]; }
        REP7(OUTI)

        // ---- L2 normalize (single-inst sqrt; div path unchanged) ----
        float ss = 0.f;
#define SSQ(i) ss = fmaf(u[i], u[i], ss);
        REP7(SSQ)
        float inv = __fdividef(1.0f, __builtin_amdgcn_sqrtf(ss) + 1e-8f);

        // ---- damped update + convergence (exact sqrtf kept for the flag) ----
        float dd = 0.f;
#define UPD(i) { float un = u[i] * inv; float mn = 0.5f * mu[i] + 0.5f * un; \
        float d = mn - mu[i]; dd = fmaf(d, d, dd); mu[i] = mn; }
        REP7(UPD)
        if (sqrtf(dd) < 1e-4f) conv = 1.0f;
    }

#define ST(i) out_mu[(size_t)row * SD + (i)] = mu[i];
    REP7(ST)
    out_cv[row] = conv;
}

extern "C" void kernel_launch(void* const* d_in, const int* in_sizes, int n_in,
                              void* d_out, int out_size, void* d_ws, size_t ws_size,
                              hipStream_t stream) {
    const float* s7  = (const float*)d_in[0];
    const float* w0  = (const float*)d_in[1];
    const float* b0  = (const float*)d_in[2];
    const float* lns = (const float*)d_in[3];
    const float* lnb = (const float*)d_in[4];
    const float* ow  = (const float*)d_in[5];
    const float* ob  = (const float*)d_in[6];
    const int Bn = in_sizes[0] / SD;

    float* out_mu = (float*)d_out;
    float* out_cv = out_mu + (size_t)Bn * SD;
    float* ws     = (float*)d_ws;            // owt[448] | lsbI[128]
    float* owt    = ws;
    float* lsb    = ws + HID * SD;

    hipLaunchKernelGGL(prep_kernel, dim3(1), dim3(640), 0, stream, ow, lns, lnb, ws);

    const int block = 256;
    const int grid  = (Bn + block - 1) / block;
    hipLaunchKernelGGL(strange_loop_kernel, dim3(grid), dim3(block), 0, stream,
                       s7, w0, b0, owt, lsb, ob, out_mu, out_cv, Bn);
}